// Round 8
// baseline (436.498 us; speedup 1.0000x reference)
//
#include <hip/hip_runtime.h>
#include <math.h>

#define LRELU_SLOPE 0.01f
#define BN_EPS 1e-5f
#define WQ_SCALE 1048576.0f        /* 2^20 fixed-point for per-dst weighted degree */
#define WQ_INV   9.5367431640625e-7f

static inline int ceil_div(int a, int b) { return (a + b - 1) / b; }

typedef _Float16 f16;
typedef f16 h4_t __attribute__((ext_vector_type(4)));
typedef f16 h8_t __attribute__((ext_vector_type(8)));
typedef float f32x4 __attribute__((ext_vector_type(4)));

// bf16 helpers: storage is high 16 bits of fp32, RNE rounding on store.
__device__ __forceinline__ unsigned short f2bf(float f) {
  unsigned int u = __float_as_uint(f);
  u = u + 0x7FFFu + ((u >> 16) & 1u);
  return (unsigned short)(u >> 16);
}
#define BF2F(u) __uint_as_float(((unsigned int)(u)) << 16)

// ============ Phase B1: per-(bucket,block) histogram, bucket = dst>>7 ============
// LDS atomics only. R6 lesson: device-scope atomics to random node counters are
// ~90ns memory-side RMWs on MI355X (k_deg: 141us) -- keep the bucket pipeline.
__launch_bounds__(1024)
__global__ void b1_hist(const int* __restrict__ ei, int* __restrict__ histT,
                        int E, int chunk, int nbuck) {
  __shared__ unsigned int hist[1024];
  const int t = threadIdx.x;
  const int blk = blockIdx.x;
  hist[t] = 0;
  __syncthreads();
  const int e0 = blk * chunk;
  const int e1 = min(e0 + chunk, E);
  for (int e = e0 + t; e < e1; e += 1024) {
    int d = ei[E + e];
    atomicAdd(&hist[d >> 7], 1u);
  }
  __syncthreads();
  if (t < nbuck) histT[(size_t)t * 256 + blk] = (int)hist[t];
}

// ============ int exclusive scan (2-level), M up to 256*1024 ============
__global__ void scan1i(const int* __restrict__ in, int* __restrict__ out,
                       int* __restrict__ bsum, int n) {
  __shared__ int lds[256];
  const int t = threadIdx.x;
  const int base = blockIdx.x * 1024 + t * 4;
  int v0 = 0, v1 = 0, v2 = 0, v3 = 0;
  if (base + 0 < n) v0 = in[base + 0];
  if (base + 1 < n) v1 = in[base + 1];
  if (base + 2 < n) v2 = in[base + 2];
  if (base + 3 < n) v3 = in[base + 3];
  int s = v0 + v1 + v2 + v3;
  lds[t] = s;
  __syncthreads();
#pragma unroll
  for (int off = 1; off < 256; off <<= 1) {
    int y = 0;
    if (t >= off) y = lds[t - off];
    __syncthreads();
    if (t >= off) lds[t] += y;
    __syncthreads();
  }
  int incl = lds[t];
  int excl = incl - s;
  if (base + 0 < n) out[base + 0] = excl;
  if (base + 1 < n) out[base + 1] = excl + v0;
  if (base + 2 < n) out[base + 2] = excl + v0 + v1;
  if (base + 3 < n) out[base + 3] = excl + v0 + v1 + v2;
  if (t == 255) bsum[blockIdx.x] = incl;
}

__global__ void scan2i(int* __restrict__ bsum, int nb) {  // in-place exclusive, nb<=256
  __shared__ int lds[256];
  int t = threadIdx.x;
  int v = (t < nb) ? bsum[t] : 0;
  lds[t] = v;
  __syncthreads();
#pragma unroll
  for (int off = 1; off < 256; off <<= 1) {
    int y = 0;
    if (t >= off) y = lds[t - off];
    __syncthreads();
    if (t >= off) lds[t] += y;
    __syncthreads();
  }
  if (t < nb) bsum[t] = lds[t] - v;
}

__global__ void scan3i(int* __restrict__ data, const int* __restrict__ bscan, int n) {
  int i = blockIdx.x * blockDim.x + threadIdx.x;
  if (i < n) data[i] += bscan[i >> 10];
}

// ============ Phase B3: scatter edges into bucket-grouped array ============
__launch_bounds__(1024)
__global__ void b3_scatter(const int* __restrict__ ei, const float* __restrict__ w,
                           const int* __restrict__ histS,
                           unsigned long long* __restrict__ bucketed,
                           int E, int chunk, int nbuck) {
  __shared__ unsigned int cursor[1024];
  const int t = threadIdx.x;
  const int blk = blockIdx.x;
  cursor[t] = (t < nbuck) ? (unsigned int)histS[(size_t)t * 256 + blk] : 0u;
  __syncthreads();
  const int e0 = blk * chunk;
  const int e1 = min(e0 + chunk, E);
  for (int e = e0 + t; e < e1; e += 1024) {
    int s = ei[e];
    int d = ei[E + e];
    unsigned int pos = atomicAdd(&cursor[d >> 7], 1u);
    unsigned long long p = ((unsigned long long)(unsigned int)(d & 127) << 57) |
                           ((unsigned long long)(unsigned int)s << 32) |
                           (unsigned long long)__float_as_uint(w[e]);
    bucketed[pos] = p;
  }
}

// ============ Phase C1: per-bucket degree + rowstart (LDS only) ============
__launch_bounds__(256)
__global__ void c1_degree(const unsigned long long* __restrict__ bucketed,
                          const int* __restrict__ histS,
                          int* __restrict__ rowstart, float* __restrict__ dinv,
                          int N, int E, int nbuck) {
  __shared__ unsigned int cnt[128], wsum[128];
  __shared__ int sc[128];
  const int t = threadIdx.x;
  const int b = blockIdx.x;
  if (t < 128) { cnt[t] = 0; wsum[t] = 0; }
  __syncthreads();
  const int r0 = histS[(size_t)b * 256];
  const int r1 = (b + 1 < nbuck) ? histS[(size_t)(b + 1) * 256] : E;
  for (int r = r0 + t; r < r1; r += 256) {
    unsigned long long p = bucketed[r];
    int d7 = (int)(p >> 57);
    float wv = __uint_as_float((unsigned int)p);
    atomicAdd(&cnt[d7], 1u);
    atomicAdd(&wsum[d7], (unsigned int)__float2uint_rn(wv * WQ_SCALE));
  }
  __syncthreads();
  if (t < 128) sc[t] = (int)cnt[t];
  __syncthreads();
#pragma unroll
  for (int off = 1; off < 128; off <<= 1) {
    int y = 0;
    if (t < 128 && t >= off) y = sc[t - off];
    __syncthreads();
    if (t < 128 && t >= off) sc[t] += y;
    __syncthreads();
  }
  if (t < 128) {
    int node = (b << 7) + t;
    if (node < N) {
      rowstart[node] = r0 + sc[t] - (int)cnt[t];   // exclusive
      float deg = 1.0f + (float)wsum[t] * WQ_INV;  // self-loop + edge weights
      dinv[node] = rsqrtf(deg);
    }
  }
  if (b == 0 && t == 0) rowstart[N] = E;
}

// ============ Phase C2: per-bucket CSR fill ============
__launch_bounds__(256)
__global__ void c2_fill(const unsigned long long* __restrict__ bucketed,
                        const int* __restrict__ histS,
                        const int* __restrict__ rowstart, const float* __restrict__ dinv,
                        unsigned long long* __restrict__ colval,
                        int N, int E, int nbuck) {
  __shared__ unsigned int cursor[128];
  const int t = threadIdx.x;
  const int b = blockIdx.x;
  if (t < 128) {
    int node = (b << 7) + t;
    cursor[t] = (node < N) ? (unsigned int)rowstart[node] : 0u;
  }
  __syncthreads();
  const int r0 = histS[(size_t)b * 256];
  const int r1 = (b + 1 < nbuck) ? histS[(size_t)(b + 1) * 256] : E;
  for (int r = r0 + t; r < r1; r += 256) {
    unsigned long long p = bucketed[r];
    int d7 = (int)(p >> 57);
    int s = (int)((p >> 32) & 0x1FFFFFF);
    float wv = __uint_as_float((unsigned int)p);
    unsigned int pos = atomicAdd(&cursor[d7], 1u);
    float v = wv * dinv[s];
    colval[pos] = ((unsigned long long)(unsigned int)s << 32) |
                  (unsigned long long)__float_as_uint(v);
  }
}

// ============ degree-sort: per-(bin,block) histogram, bin = min(deg,255) ========
// k_agg waves co-schedule 4 rows/wave; trip count = max of the 4 degrees.
// Sorting rows by degree removes the exec-masked idle (~25% of loop slots).
__launch_bounds__(256)
__global__ void d1_hist(const int* __restrict__ rowstart, int* __restrict__ histT,
                        int N, int chunk) {
  __shared__ unsigned int hist[256];
  const int t = threadIdx.x;
  const int blk = blockIdx.x;
  hist[t] = 0;
  __syncthreads();
  const int i0 = blk * chunk;
  const int i1 = min(i0 + chunk, N);
  for (int i = i0 + t; i < i1; i += 256) {
    int deg = rowstart[i + 1] - rowstart[i];
    atomicAdd(&hist[min(deg, 255)], 1u);
  }
  __syncthreads();
  histT[(size_t)t * 256 + blk] = (int)hist[t];
}

__launch_bounds__(256)
__global__ void d3_scatter(const int* __restrict__ rowstart, const int* __restrict__ histS,
                           int* __restrict__ order, int N, int chunk) {
  __shared__ unsigned int cursor[256];
  const int t = threadIdx.x;
  const int blk = blockIdx.x;
  cursor[t] = (unsigned int)histS[(size_t)t * 256 + blk];
  __syncthreads();
  const int i0 = blk * chunk;
  const int i1 = min(i0 + chunk, N);
  for (int i = i0 + t; i < i1; i += 256) {
    int deg = rowstart[i + 1] - rowstart[i];
    unsigned int pos = atomicAdd(&cursor[min(deg, 255)], 1u);
    order[pos] = i;
  }
}

// ---------------- MFMA GEMM: H16[N,64] = bf16(lrelu(bn(X))[N,K] @ W[K,64]) -------
// IN16==1: X is bf16 [N,64] (inter-layer buffers stored bf16 to halve traffic).
template <int K, int BN, int IN16>
__launch_bounds__(256, 4)
__global__ void k_gemm(const void* __restrict__ Xv, const float* __restrict__ W,
                       unsigned short* __restrict__ H16,
                       const float* __restrict__ s, const float* __restrict__ ss,
                       const float* __restrict__ g, const float* __restrict__ be,
                       int N) {
  constexpr int KP = K + 8;          // row pitch in f16; keeps rows 16B-aligned
  constexpr int KQ = K / 4;
  __shared__ f16 Xl[64 * KP];        // [node-in-tile][k]
  __shared__ f16 Wt[64 * KP];        // [outcol][k]  (transposed W)
  __shared__ float scaleC[64], shiftC[64];
  const int t = threadIdx.x;
  const int n0 = blockIdx.x * 64;

  if (BN) {
    if (t < 64) {
      float invN = 1.0f / (float)N;
      float mean = s[t] * invN;
      float var = ss[t] * invN - mean * mean;
      float sc = g[t] * rsqrtf(var + BN_EPS);
      scaleC[t] = sc;
      shiftC[t] = be[t] - mean * sc;
    }
    __syncthreads();
  }

  // ---- stage X tile (64 x K) as f16, with optional BN+lrelu ----
  for (int idx = t; idx < 64 * KQ; idx += 256) {
    int row = idx / KQ;
    int kq = idx % KQ;
    int gn = n0 + row;
    float4 v = make_float4(0.f, 0.f, 0.f, 0.f);
    if (gn < N) {
      if (IN16) {
        ushort4 u = *(const ushort4*)((const unsigned short*)Xv + (size_t)gn * K + 4 * kq);
        v = make_float4(BF2F(u.x), BF2F(u.y), BF2F(u.z), BF2F(u.w));
      } else {
        v = *(const float4*)((const float*)Xv + (size_t)gn * K + 4 * kq);
      }
    }
    if (BN) {  // K==64: column index is 4*kq+j
      int c = 4 * kq;
      float a;
      a = v.x * scaleC[c + 0] + shiftC[c + 0]; v.x = (a > 0.f) ? a : LRELU_SLOPE * a;
      a = v.y * scaleC[c + 1] + shiftC[c + 1]; v.y = (a > 0.f) ? a : LRELU_SLOPE * a;
      a = v.z * scaleC[c + 2] + shiftC[c + 2]; v.z = (a > 0.f) ? a : LRELU_SLOPE * a;
      a = v.w * scaleC[c + 3] + shiftC[c + 3]; v.w = (a > 0.f) ? a : LRELU_SLOPE * a;
    }
    h4_t hv = { (f16)v.x, (f16)v.y, (f16)v.z, (f16)v.w };
    *(h4_t*)(Xl + row * KP + 4 * kq) = hv;
  }
  // ---- stage W (K x 64) transposed to Wt[col][k] as f16 ----
  for (int idx = t; idx < K * 16; idx += 256) {
    int k = idx >> 4;
    int c4 = idx & 15;
    float4 wv = *(const float4*)(W + (size_t)k * 64 + 4 * c4);
    Wt[(4 * c4 + 0) * KP + k] = (f16)wv.x;
    Wt[(4 * c4 + 1) * KP + k] = (f16)wv.y;
    Wt[(4 * c4 + 2) * KP + k] = (f16)wv.z;
    Wt[(4 * c4 + 3) * KP + k] = (f16)wv.w;
  }
  __syncthreads();

  const int lane = t & 63;
  const int wv = t >> 6;             // wave id: rows [16*wv, 16*wv+16)
  const int fr = lane & 15;
  const int fc = lane >> 4;

  f32x4 acc0 = {0.f, 0.f, 0.f, 0.f};
  f32x4 acc1 = {0.f, 0.f, 0.f, 0.f};
  f32x4 acc2 = {0.f, 0.f, 0.f, 0.f};
  f32x4 acc3 = {0.f, 0.f, 0.f, 0.f};

  const f16* ap = Xl + (16 * wv + fr) * KP + 8 * fc;
  const f16* bp0 = Wt + (0 + fr) * KP + 8 * fc;
  const f16* bp1 = Wt + (16 + fr) * KP + 8 * fc;
  const f16* bp2 = Wt + (32 + fr) * KP + 8 * fc;
  const f16* bp3 = Wt + (48 + fr) * KP + 8 * fc;

#pragma unroll
  for (int kt = 0; kt < K; kt += 32) {
    h8_t a = *(const h8_t*)(ap + kt);
    acc0 = __builtin_amdgcn_mfma_f32_16x16x32_f16(a, *(const h8_t*)(bp0 + kt), acc0, 0, 0, 0);
    acc1 = __builtin_amdgcn_mfma_f32_16x16x32_f16(a, *(const h8_t*)(bp1 + kt), acc1, 0, 0, 0);
    acc2 = __builtin_amdgcn_mfma_f32_16x16x32_f16(a, *(const h8_t*)(bp2 + kt), acc2, 0, 0, 0);
    acc3 = __builtin_amdgcn_mfma_f32_16x16x32_f16(a, *(const h8_t*)(bp3 + kt), acc3, 0, 0, 0);
  }

  // D: col = 16*n + fr, row-in-tile = 16*wv + 4*fc + r
#pragma unroll
  for (int r = 0; r < 4; ++r) {
    int node = n0 + 16 * wv + 4 * fc + r;
    if (node < N) {
      size_t base = (size_t)node * 64 + fr;
      H16[base + 0]  = f2bf(acc0[r]);
      H16[base + 16] = f2bf(acc1[r]);
      H16[base + 32] = f2bf(acc2[r]);
      H16[base + 48] = f2bf(acc3[r]);
    }
  }
}

// ---------------- CSR aggregation, bf16 gather + 8-way MLP (R2-proven) ---------
// out[d] = dinv[d]*sum(val*h[src]) + dinv[d]^2*h[d] + b  (fp32 accumulate)
// Rows processed in degree-sorted order (order[]): all 4 groups of a wave get
// equal trip counts -> no exec-masked idle.
// STATS==1: also emit per-block column sum/sumsq partials (fp32, pre-rounding).
// OUT16==1: store hout as bf16 (consumer is next k_gemm which converts to f16).
#define AGG_GATH(cv) (*(const ushort4*)(h16 + ((size_t)((cv) >> 32)) * 64 + lane * 4))
#define AGG_FMA(a, cv, h)                                     \
  {                                                           \
    float v_ = __uint_as_float((unsigned int)(cv));           \
    (a).x += v_ * BF2F((h).x); (a).y += v_ * BF2F((h).y);     \
    (a).z += v_ * BF2F((h).z); (a).w += v_ * BF2F((h).w);     \
  }
template <int STATS, int LRELU, int OUT16>
__launch_bounds__(256)
__global__ void k_agg(const unsigned short* __restrict__ h16, void* __restrict__ hout,
                      const float* __restrict__ bias, const float* __restrict__ dinv,
                      const int* __restrict__ rowstart,
                      const unsigned long long* __restrict__ colval,
                      const int* __restrict__ order,
                      float* __restrict__ partial, int N) {
  __shared__ float4 rs[STATS ? 256 : 1];
  __shared__ float4 rq[STATS ? 256 : 1];
  const int t = threadIdx.x;
  const int grp = t >> 4;
  const int lane = t & 15;
  const int idx = blockIdx.x * 16 + grp;
  const bool valid = (idx < N);
  const int d = valid ? order[idx] : 0;
  int r0 = 0, r1 = 0;
  if (valid) { r0 = rowstart[d]; r1 = rowstart[d + 1]; }
  float4 a0 = make_float4(0.f, 0.f, 0.f, 0.f);
  float4 a1 = make_float4(0.f, 0.f, 0.f, 0.f);
  float4 a2 = make_float4(0.f, 0.f, 0.f, 0.f);
  float4 a3 = make_float4(0.f, 0.f, 0.f, 0.f);
  int r = r0;
  for (; r + 8 <= r1; r += 8) {
    unsigned long long cv0 = colval[r + 0];
    unsigned long long cv1 = colval[r + 1];
    unsigned long long cv2 = colval[r + 2];
    unsigned long long cv3 = colval[r + 3];
    unsigned long long cv4 = colval[r + 4];
    unsigned long long cv5 = colval[r + 5];
    unsigned long long cv6 = colval[r + 6];
    unsigned long long cv7 = colval[r + 7];
    ushort4 h0 = AGG_GATH(cv0);
    ushort4 h1 = AGG_GATH(cv1);
    ushort4 h2 = AGG_GATH(cv2);
    ushort4 h3 = AGG_GATH(cv3);
    ushort4 h4 = AGG_GATH(cv4);
    ushort4 h5 = AGG_GATH(cv5);
    ushort4 h6 = AGG_GATH(cv6);
    ushort4 h7 = AGG_GATH(cv7);
    AGG_FMA(a0, cv0, h0); AGG_FMA(a1, cv1, h1);
    AGG_FMA(a2, cv2, h2); AGG_FMA(a3, cv3, h3);
    AGG_FMA(a0, cv4, h4); AGG_FMA(a1, cv5, h5);
    AGG_FMA(a2, cv6, h6); AGG_FMA(a3, cv7, h7);
  }
  for (; r + 4 <= r1; r += 4) {
    unsigned long long cv0 = colval[r + 0];
    unsigned long long cv1 = colval[r + 1];
    unsigned long long cv2 = colval[r + 2];
    unsigned long long cv3 = colval[r + 3];
    ushort4 h0 = AGG_GATH(cv0);
    ushort4 h1 = AGG_GATH(cv1);
    ushort4 h2 = AGG_GATH(cv2);
    ushort4 h3 = AGG_GATH(cv3);
    AGG_FMA(a0, cv0, h0); AGG_FMA(a1, cv1, h1);
    AGG_FMA(a2, cv2, h2); AGG_FMA(a3, cv3, h3);
  }
  for (; r < r1; ++r) {
    unsigned long long cv = colval[r];
    ushort4 hv = AGG_GATH(cv);
    AGG_FMA(a0, cv, hv);
  }
  float4 acc;
  acc.x = (a0.x + a1.x) + (a2.x + a3.x);
  acc.y = (a0.y + a1.y) + (a2.y + a3.y);
  acc.z = (a0.z + a1.z) + (a2.z + a3.z);
  acc.w = (a0.w + a1.w) + (a2.w + a3.w);
  float di = valid ? dinv[d] : 0.f;
  float di2 = di * di;
  ushort4 hd4 = make_ushort4(0, 0, 0, 0);
  if (valid) hd4 = *(const ushort4*)(h16 + (size_t)d * 64 + lane * 4);
  float4 b4 = *(const float4*)(bias + lane * 4);
  float4 o;
  o.x = di * acc.x + di2 * BF2F(hd4.x) + b4.x;
  o.y = di * acc.y + di2 * BF2F(hd4.y) + b4.y;
  o.z = di * acc.z + di2 * BF2F(hd4.z) + b4.z;
  o.w = di * acc.w + di2 * BF2F(hd4.w) + b4.w;
  if (LRELU) {
    o.x = (o.x > 0.f) ? o.x : LRELU_SLOPE * o.x;
    o.y = (o.y > 0.f) ? o.y : LRELU_SLOPE * o.y;
    o.z = (o.z > 0.f) ? o.z : LRELU_SLOPE * o.z;
    o.w = (o.w > 0.f) ? o.w : LRELU_SLOPE * o.w;
  }
  if (!valid) o = make_float4(0.f, 0.f, 0.f, 0.f);
  if (valid) {
    if (OUT16) {
      ushort4 o16;
      o16.x = f2bf(o.x); o16.y = f2bf(o.y); o16.z = f2bf(o.z); o16.w = f2bf(o.w);
      *(ushort4*)((unsigned short*)hout + (size_t)d * 64 + lane * 4) = o16;
    } else {
      *(float4*)((float*)hout + (size_t)d * 64 + lane * 4) = o;
    }
  }

  if (STATS) {
    rs[t] = o;
    rq[t] = make_float4(o.x * o.x, o.y * o.y, o.z * o.z, o.w * o.w);
    __syncthreads();
#pragma unroll
    for (int st = 8; st >= 1; st >>= 1) {
      if ((t >> 4) < st) {
        float4 sa = rs[t], sb = rs[t + st * 16];
        float4 qa = rq[t], qb = rq[t + st * 16];
        rs[t] = make_float4(sa.x + sb.x, sa.y + sb.y, sa.z + sb.z, sa.w + sb.w);
        rq[t] = make_float4(qa.x + qb.x, qa.y + qb.y, qa.z + qb.z, qa.w + qb.w);
      }
      __syncthreads();
    }
    if (t < 16) {
      float4 sv = rs[t], qv = rq[t];
      float* ps = partial + (size_t)blockIdx.x * 128 + 4 * t;
      ps[0] = sv.x; ps[1] = sv.y; ps[2] = sv.z; ps[3] = sv.w;
      ps[64] = qv.x; ps[65] = qv.y; ps[66] = qv.z; ps[67] = qv.w;
    }
  }
}

// Parallel reduce: 128 blocks (one per output column), 256 threads each.
__global__ void k_stats_reduce(const float* __restrict__ partial, float* __restrict__ s,
                               float* __restrict__ ss, int nb) {
  __shared__ float red[256];
  const int c = blockIdx.x;   // 0..127
  const int t = threadIdx.x;  // 0..255
  float a = 0.f;
  for (int b = t; b < nb; b += 256) a += partial[(size_t)b * 128 + c];
  red[t] = a;
  __syncthreads();
  for (int st = 128; st >= 1; st >>= 1) {
    if (t < st) red[t] += red[t + st];
    __syncthreads();
  }
  if (t == 0) {
    if (c < 64) s[c] = red[0];
    else ss[c - 64] = red[0];
  }
}

// ---------------- graph boundaries from sorted batch (atomic-free) ----------------
__global__ void k_gbounds(const int* __restrict__ batch, int* __restrict__ gstart,
                          int N, int G) {
  int i = blockIdx.x * blockDim.x + threadIdx.x;
  if (i >= N) return;
  int b = batch[i];
  int prev = (i == 0) ? -1 : batch[i - 1];
  for (int g = prev + 1; g <= b; ++g) gstart[g] = i;   // batch sorted => prev <= b
  if (i == N - 1) {
    for (int g = b + 1; g <= G; ++g) gstart[g] = N;
  }
}

// ---------------- pooling (max & mean per graph) + FC, fused ----------------
__launch_bounds__(256)
__global__ void k_pool(const float* __restrict__ h, const int* __restrict__ gstart,
                       const float* __restrict__ Wfc, const float* __restrict__ bfc,
                       float* __restrict__ out, int G) {
  __shared__ float lmx[256], lsm[256], red[128];
  const int g = blockIdx.x;
  const int t = threadIdx.x;
  const int c = t & 63;
  const int sub = t >> 6;
  const int n0 = gstart[g];
  const int n1 = gstart[g + 1];
  float mx = -INFINITY, sm = 0.f;
  for (int n = n0 + sub; n < n1; n += 4) {
    float v = h[(size_t)n * 64 + c];
    mx = fmaxf(mx, v);
    sm += v;
  }
  lmx[t] = mx;
  lsm[t] = sm;
  __syncthreads();
  if (t < 64) {
    mx = fmaxf(fmaxf(lmx[t], lmx[t + 64]), fmaxf(lmx[t + 128], lmx[t + 192]));
    sm = lsm[t] + lsm[t + 64] + lsm[t + 128] + lsm[t + 192];
    float cntf = (float)(n1 - n0);
    float mean = sm / fmaxf(cntf, 1.0f);
    red[t] = mx * Wfc[t];
    red[t + 64] = mean * Wfc[64 + t];
  }
  __syncthreads();
  for (int st = 64; st >= 1; st >>= 1) {
    if (t < st) red[t] += red[t + st];
    __syncthreads();
  }
  if (t == 0) out[g] = red[0] + bfc[0];
}

// ---------------- host launch ----------------
extern "C" void kernel_launch(void* const* d_in, const int* in_sizes, int n_in,
                              void* d_out, int out_size, void* d_ws, size_t ws_size,
                              hipStream_t stream) {
  const float* x = (const float*)d_in[0];
  const int* ei = (const int*)d_in[1];
  const int* batch = (const int*)d_in[2];
  const float* eattr = (const float*)d_in[3];
  const float* W0 = (const float*)d_in[4];
  const float* b0 = (const float*)d_in[5];
  const float* g0 = (const float*)d_in[6];
  const float* be0 = (const float*)d_in[7];
  const float* W1 = (const float*)d_in[8];
  const float* b1 = (const float*)d_in[9];
  const float* g1 = (const float*)d_in[10];
  const float* be1 = (const float*)d_in[11];
  const float* W2 = (const float*)d_in[12];
  const float* b2 = (const float*)d_in[13];
  const float* W3 = (const float*)d_in[14];
  const float* b3 = (const float*)d_in[15];
  const float* Wfc = (const float*)d_in[16];
  const float* bfc = (const float*)d_in[17];
  float* out = (float*)d_out;

  const int N = in_sizes[2];       // batch is [N]
  const int E = in_sizes[3];       // edge_attr is [E]
  const int CIN = in_sizes[0] / N; // 128
  const int G = out_size;          // [G,1]
  const int nbuck = ceil_div(N, 128);
  const int chunk = ceil_div(E, 256);
  const int chunkN = ceil_div(N, 256);
  const int M = nbuck * 256;       // hist matrix elements
  const int nag = ceil_div(N, 16); // k_agg blocks

  // workspace carve-up (256B-aligned slices)
  size_t off = 0;
  auto alloc = [&](size_t bytes) -> void* {
    void* p = (char*)d_ws + off;
    off += (bytes + 255) & ~(size_t)255;
    return p;
  };
  int* histT = (int*)alloc((size_t)1024 * 256 * 4);   // raw counts [bucket][block]
  int* histS = (int*)alloc((size_t)1024 * 256 * 4);   // scanned
  int* bsum = (int*)alloc(1024 * 4);
  unsigned long long* bucketed = (unsigned long long*)alloc((size_t)E * 8);
  float* dinv = (float*)alloc((size_t)N * 4);
  int* rowstart = (int*)alloc((size_t)(N + 1) * 4);
  unsigned long long* colval = (unsigned long long*)alloc((size_t)E * 8);
  int* order = (int*)alloc((size_t)N * 4);
  unsigned short* A16 = (unsigned short*)alloc((size_t)N * 64 * 2);
  unsigned short* B16 = (unsigned short*)alloc((size_t)N * 64 * 2);
  float* A = (float*)alloc((size_t)N * 64 * 4);       // final layer out (pool input)
  unsigned short* H16 = (unsigned short*)alloc((size_t)N * 64 * 2);
  float* sums = (float*)alloc(256 * 4);   // s0|ss0|s1|ss1
  float* partial = (float*)alloc((size_t)nag * 128 * 4);
  int* gstart = (int*)alloc((size_t)(G + 1) * 4);
  (void)ws_size; (void)n_in; (void)CIN;

  // ---- graph structure (layer-invariant, zero device-scope atomics) ----
  b1_hist<<<256, 1024, 0, stream>>>(ei, histT, E, chunk, nbuck);
  const int nbs = ceil_div(M, 1024);
  scan1i<<<nbs, 256, 0, stream>>>(histT, histS, bsum, M);
  scan2i<<<1, 256, 0, stream>>>(bsum, nbs);
  scan3i<<<ceil_div(M, 256), 256, 0, stream>>>(histS, bsum, M);
  b3_scatter<<<256, 1024, 0, stream>>>(ei, eattr, histS, bucketed, E, chunk, nbuck);
  c1_degree<<<nbuck, 256, 0, stream>>>(bucketed, histS, rowstart, dinv, N, E, nbuck);
  c2_fill<<<nbuck, 256, 0, stream>>>(bucketed, histS, rowstart, dinv, colval, N, E, nbuck);
  // ---- degree-sort rows (reuses histT/histS/bsum, dead after c2_fill) ----
  d1_hist<<<256, 256, 0, stream>>>(rowstart, histT, N, chunkN);
  const int M2 = 256 * 256;
  const int nbs2 = ceil_div(M2, 1024);
  scan1i<<<nbs2, 256, 0, stream>>>(histT, histS, bsum, M2);
  scan2i<<<1, 256, 0, stream>>>(bsum, nbs2);
  scan3i<<<ceil_div(M2, 256), 256, 0, stream>>>(histS, bsum, M2);
  d3_scatter<<<256, 256, 0, stream>>>(rowstart, histS, order, N, chunkN);
  k_gbounds<<<ceil_div(N, 256), 256, 0, stream>>>(batch, gstart, N, G);

  // layer 0: gemm(x,W0)->H16; agg(+stats) H16->B16; reduce
  k_gemm<128, 0, 0><<<ceil_div(N, 64), 256, 0, stream>>>(x, W0, H16, nullptr, nullptr, nullptr, nullptr, N);
  k_agg<1, 0, 1><<<nag, 256, 0, stream>>>(H16, B16, b0, dinv, rowstart, colval, order, partial, N);
  k_stats_reduce<<<128, 256, 0, stream>>>(partial, sums + 0, sums + 64, nag);

  // layer 1: gemm(bn0+lrelu(B16),W1)->H16 (fused); agg(+stats) H16->A16; reduce
  k_gemm<64, 1, 1><<<ceil_div(N, 64), 256, 0, stream>>>(B16, W1, H16, sums + 0, sums + 64, g0, be0, N);
  k_agg<1, 0, 1><<<nag, 256, 0, stream>>>(H16, A16, b1, dinv, rowstart, colval, order, partial, N);
  k_stats_reduce<<<128, 256, 0, stream>>>(partial, sums + 128, sums + 192, nag);

  // layer 2: gemm(bn1+lrelu(A16),W2)->H16 (fused); agg(+lrelu) H16->B16
  k_gemm<64, 1, 1><<<ceil_div(N, 64), 256, 0, stream>>>(A16, W2, H16, sums + 128, sums + 192, g1, be1, N);
  k_agg<0, 1, 1><<<nag, 256, 0, stream>>>(H16, B16, b2, dinv, rowstart, colval, order, nullptr, N);

  // layer 3: gemm(B16,W3)->H16; agg(+lrelu) H16->A (fp32 for pool)
  k_gemm<64, 0, 1><<<ceil_div(N, 64), 256, 0, stream>>>(B16, W3, H16, nullptr, nullptr, nullptr, nullptr, N);
  k_agg<0, 1, 0><<<nag, 256, 0, stream>>>(H16, A, b3, dinv, rowstart, colval, order, nullptr, N);

  // pooling + FC
  k_pool<<<G, 256, 0, stream>>>(A, gstart, Wfc, bfc, out, G);
}

// Round 9
// 419.536 us; speedup vs baseline: 1.0404x; 1.0404x over previous
//
#include <hip/hip_runtime.h>
#include <math.h>

#define LRELU_SLOPE 0.01f
#define BN_EPS 1e-5f
#define WQ_SCALE 1048576.0f        /* 2^20 fixed-point for per-dst weighted degree */
#define WQ_INV   9.5367431640625e-7f

static inline int ceil_div(int a, int b) { return (a + b - 1) / b; }

typedef _Float16 f16;
typedef f16 h4_t __attribute__((ext_vector_type(4)));
typedef f16 h8_t __attribute__((ext_vector_type(8)));
typedef float f32x4 __attribute__((ext_vector_type(4)));

// bf16 helpers: storage is high 16 bits of fp32, RNE rounding on store.
__device__ __forceinline__ unsigned short f2bf(float f) {
  unsigned int u = __float_as_uint(f);
  u = u + 0x7FFFu + ((u >> 16) & 1u);
  return (unsigned short)(u >> 16);
}
#define BF2F(u) __uint_as_float(((unsigned int)(u)) << 16)

// ============ Phase B1: per-(bucket,block) histogram, bucket = dst>>7 ============
// LDS atomics only. R6 lesson: device-scope atomics to random node counters are
// ~90ns memory-side RMWs on MI355X (k_deg: 141us) -- keep the bucket pipeline.
__launch_bounds__(1024)
__global__ void b1_hist(const int* __restrict__ ei, int* __restrict__ histT,
                        int E, int chunk, int nbuck) {
  __shared__ unsigned int hist[1024];
  const int t = threadIdx.x;
  const int blk = blockIdx.x;
  hist[t] = 0;
  __syncthreads();
  const int e0 = blk * chunk;
  const int e1 = min(e0 + chunk, E);
  for (int e = e0 + t; e < e1; e += 1024) {
    int d = ei[E + e];
    atomicAdd(&hist[d >> 7], 1u);
  }
  __syncthreads();
  if (t < nbuck) histT[(size_t)t * 256 + blk] = (int)hist[t];
}

// ============ int exclusive scan (2-level), M up to 256*1024 ============
__global__ void scan1i(const int* __restrict__ in, int* __restrict__ out,
                       int* __restrict__ bsum, int n) {
  __shared__ int lds[256];
  const int t = threadIdx.x;
  const int base = blockIdx.x * 1024 + t * 4;
  int v0 = 0, v1 = 0, v2 = 0, v3 = 0;
  if (base + 0 < n) v0 = in[base + 0];
  if (base + 1 < n) v1 = in[base + 1];
  if (base + 2 < n) v2 = in[base + 2];
  if (base + 3 < n) v3 = in[base + 3];
  int s = v0 + v1 + v2 + v3;
  lds[t] = s;
  __syncthreads();
#pragma unroll
  for (int off = 1; off < 256; off <<= 1) {
    int y = 0;
    if (t >= off) y = lds[t - off];
    __syncthreads();
    if (t >= off) lds[t] += y;
    __syncthreads();
  }
  int incl = lds[t];
  int excl = incl - s;
  if (base + 0 < n) out[base + 0] = excl;
  if (base + 1 < n) out[base + 1] = excl + v0;
  if (base + 2 < n) out[base + 2] = excl + v0 + v1;
  if (base + 3 < n) out[base + 3] = excl + v0 + v1 + v2;
  if (t == 255) bsum[blockIdx.x] = incl;
}

__global__ void scan2i(int* __restrict__ bsum, int nb) {  // in-place exclusive, nb<=256
  __shared__ int lds[256];
  int t = threadIdx.x;
  int v = (t < nb) ? bsum[t] : 0;
  lds[t] = v;
  __syncthreads();
#pragma unroll
  for (int off = 1; off < 256; off <<= 1) {
    int y = 0;
    if (t >= off) y = lds[t - off];
    __syncthreads();
    if (t >= off) lds[t] += y;
    __syncthreads();
  }
  if (t < nb) bsum[t] = lds[t] - v;
}

__global__ void scan3i(int* __restrict__ data, const int* __restrict__ bscan, int n) {
  int i = blockIdx.x * blockDim.x + threadIdx.x;
  if (i < n) data[i] += bscan[i >> 10];
}

// ============ Phase B3: scatter edges into bucket-grouped array ============
__launch_bounds__(1024)
__global__ void b3_scatter(const int* __restrict__ ei, const float* __restrict__ w,
                           const int* __restrict__ histS,
                           unsigned long long* __restrict__ bucketed,
                           int E, int chunk, int nbuck) {
  __shared__ unsigned int cursor[1024];
  const int t = threadIdx.x;
  const int blk = blockIdx.x;
  cursor[t] = (t < nbuck) ? (unsigned int)histS[(size_t)t * 256 + blk] : 0u;
  __syncthreads();
  const int e0 = blk * chunk;
  const int e1 = min(e0 + chunk, E);
  for (int e = e0 + t; e < e1; e += 1024) {
    int s = ei[e];
    int d = ei[E + e];
    unsigned int pos = atomicAdd(&cursor[d >> 7], 1u);
    unsigned long long p = ((unsigned long long)(unsigned int)(d & 127) << 57) |
                           ((unsigned long long)(unsigned int)s << 32) |
                           (unsigned long long)__float_as_uint(w[e]);
    bucketed[pos] = p;
  }
}

// ============ Phase C: merged degree + CSR fill (one bucketed HBM pass) ========
// dinv is folded into the GEMM output (H16 stores dinv[n]*h[n]), so colval
// needs only (src, w) -- no dependency on the completed dinv array -> the
// former c1/c2 pair merges; the second sweep re-reads this bucket's ~16KB of
// 'bucketed' from L1/L2 for free.
__launch_bounds__(256)
__global__ void c_build(const unsigned long long* __restrict__ bucketed,
                        const int* __restrict__ histS,
                        int* __restrict__ rowstart, float* __restrict__ dinv,
                        unsigned long long* __restrict__ colval,
                        int N, int E, int nbuck) {
  __shared__ unsigned int cnt[128], wsum[128], cursor[128];
  __shared__ int sc[128];
  const int t = threadIdx.x;
  const int b = blockIdx.x;
  if (t < 128) { cnt[t] = 0; wsum[t] = 0; }
  __syncthreads();
  const int r0 = histS[(size_t)b * 256];
  const int r1 = (b + 1 < nbuck) ? histS[(size_t)(b + 1) * 256] : E;
  for (int r = r0 + t; r < r1; r += 256) {
    unsigned long long p = bucketed[r];
    int d7 = (int)(p >> 57);
    float wv = __uint_as_float((unsigned int)p);
    atomicAdd(&cnt[d7], 1u);
    atomicAdd(&wsum[d7], (unsigned int)__float2uint_rn(wv * WQ_SCALE));
  }
  __syncthreads();
  if (t < 128) sc[t] = (int)cnt[t];
  __syncthreads();
#pragma unroll
  for (int off = 1; off < 128; off <<= 1) {
    int y = 0;
    if (t < 128 && t >= off) y = sc[t - off];
    __syncthreads();
    if (t < 128 && t >= off) sc[t] += y;
    __syncthreads();
  }
  if (t < 128) {
    int node = (b << 7) + t;
    int rst = r0 + sc[t] - (int)cnt[t];           // exclusive
    cursor[t] = (unsigned int)rst;
    if (node < N) {
      rowstart[node] = rst;
      float deg = 1.0f + (float)wsum[t] * WQ_INV; // self-loop + edge weights
      dinv[node] = rsqrtf(deg);
    }
  }
  __syncthreads();
  for (int r = r0 + t; r < r1; r += 256) {
    unsigned long long p = bucketed[r];           // L1/L2 hit (bucket ~16KB)
    int d7 = (int)(p >> 57);
    unsigned int pos = atomicAdd(&cursor[d7], 1u);
    colval[pos] = (p << 7) >> 7;                  // keep (src, w), drop d7
  }
  if (b == 0 && t == 0) rowstart[N] = E;
}

// ---------------- MFMA GEMM: H16[N,64] = bf16(dinv * lrelu(bn(X)) @ W) ---------
// dinv pre-scaling folded here (H' = dinv*h): lets k_agg use raw w and c_build
// skip the dinv dependency. IN16==1: X is bf16.
template <int K, int BN, int IN16>
__launch_bounds__(256, 4)
__global__ void k_gemm(const void* __restrict__ Xv, const float* __restrict__ W,
                       unsigned short* __restrict__ H16,
                       const float* __restrict__ dinv,
                       const float* __restrict__ s, const float* __restrict__ ss,
                       const float* __restrict__ g, const float* __restrict__ be,
                       int N) {
  constexpr int KP = K + 8;          // row pitch in f16; keeps rows 16B-aligned
  constexpr int KQ = K / 4;
  __shared__ f16 Xl[64 * KP];        // [node-in-tile][k]
  __shared__ f16 Wt[64 * KP];        // [outcol][k]  (transposed W)
  __shared__ float scaleC[64], shiftC[64];
  const int t = threadIdx.x;
  const int n0 = blockIdx.x * 64;

  if (BN) {
    if (t < 64) {
      float invN = 1.0f / (float)N;
      float mean = s[t] * invN;
      float var = ss[t] * invN - mean * mean;
      float sc = g[t] * rsqrtf(var + BN_EPS);
      scaleC[t] = sc;
      shiftC[t] = be[t] - mean * sc;
    }
    __syncthreads();
  }

  // ---- stage X tile (64 x K) as f16, with optional BN+lrelu ----
  for (int idx = t; idx < 64 * KQ; idx += 256) {
    int row = idx / KQ;
    int kq = idx % KQ;
    int gn = n0 + row;
    float4 v = make_float4(0.f, 0.f, 0.f, 0.f);
    if (gn < N) {
      if (IN16) {
        ushort4 u = *(const ushort4*)((const unsigned short*)Xv + (size_t)gn * K + 4 * kq);
        v = make_float4(BF2F(u.x), BF2F(u.y), BF2F(u.z), BF2F(u.w));
      } else {
        v = *(const float4*)((const float*)Xv + (size_t)gn * K + 4 * kq);
      }
    }
    if (BN) {  // K==64: column index is 4*kq+j
      int c = 4 * kq;
      float a;
      a = v.x * scaleC[c + 0] + shiftC[c + 0]; v.x = (a > 0.f) ? a : LRELU_SLOPE * a;
      a = v.y * scaleC[c + 1] + shiftC[c + 1]; v.y = (a > 0.f) ? a : LRELU_SLOPE * a;
      a = v.z * scaleC[c + 2] + shiftC[c + 2]; v.z = (a > 0.f) ? a : LRELU_SLOPE * a;
      a = v.w * scaleC[c + 3] + shiftC[c + 3]; v.w = (a > 0.f) ? a : LRELU_SLOPE * a;
    }
    h4_t hv = { (f16)v.x, (f16)v.y, (f16)v.z, (f16)v.w };
    *(h4_t*)(Xl + row * KP + 4 * kq) = hv;
  }
  // ---- stage W (K x 64) transposed to Wt[col][k] as f16 ----
  for (int idx = t; idx < K * 16; idx += 256) {
    int k = idx >> 4;
    int c4 = idx & 15;
    float4 wv = *(const float4*)(W + (size_t)k * 64 + 4 * c4);
    Wt[(4 * c4 + 0) * KP + k] = (f16)wv.x;
    Wt[(4 * c4 + 1) * KP + k] = (f16)wv.y;
    Wt[(4 * c4 + 2) * KP + k] = (f16)wv.z;
    Wt[(4 * c4 + 3) * KP + k] = (f16)wv.w;
  }
  __syncthreads();

  const int lane = t & 63;
  const int wv = t >> 6;             // wave id: rows [16*wv, 16*wv+16)
  const int fr = lane & 15;
  const int fc = lane >> 4;

  f32x4 acc0 = {0.f, 0.f, 0.f, 0.f};
  f32x4 acc1 = {0.f, 0.f, 0.f, 0.f};
  f32x4 acc2 = {0.f, 0.f, 0.f, 0.f};
  f32x4 acc3 = {0.f, 0.f, 0.f, 0.f};

  const f16* ap = Xl + (16 * wv + fr) * KP + 8 * fc;
  const f16* bp0 = Wt + (0 + fr) * KP + 8 * fc;
  const f16* bp1 = Wt + (16 + fr) * KP + 8 * fc;
  const f16* bp2 = Wt + (32 + fr) * KP + 8 * fc;
  const f16* bp3 = Wt + (48 + fr) * KP + 8 * fc;

#pragma unroll
  for (int kt = 0; kt < K; kt += 32) {
    h8_t a = *(const h8_t*)(ap + kt);
    acc0 = __builtin_amdgcn_mfma_f32_16x16x32_f16(a, *(const h8_t*)(bp0 + kt), acc0, 0, 0, 0);
    acc1 = __builtin_amdgcn_mfma_f32_16x16x32_f16(a, *(const h8_t*)(bp1 + kt), acc1, 0, 0, 0);
    acc2 = __builtin_amdgcn_mfma_f32_16x16x32_f16(a, *(const h8_t*)(bp2 + kt), acc2, 0, 0, 0);
    acc3 = __builtin_amdgcn_mfma_f32_16x16x32_f16(a, *(const h8_t*)(bp3 + kt), acc3, 0, 0, 0);
  }

  // D: col = 16*n + fr, row-in-tile = 16*wv + 4*fc + r
#pragma unroll
  for (int r = 0; r < 4; ++r) {
    int node = n0 + 16 * wv + 4 * fc + r;
    if (node < N) {
      float dv = dinv[node];
      size_t base = (size_t)node * 64 + fr;
      H16[base + 0]  = f2bf(acc0[r] * dv);
      H16[base + 16] = f2bf(acc1[r] * dv);
      H16[base + 32] = f2bf(acc2[r] * dv);
      H16[base + 48] = f2bf(acc3[r] * dv);
    }
  }
}

// ---------------- CSR aggregation, bf16 gather + 8-way MLP (R2-proven) ---------
// H16 holds H' = dinv*h. out[d] = dinv[d]*(sum(w*H'[src]) + H'[d]) + b.
// STATS==1: also emit per-block column sum/sumsq partials (fp32, pre-rounding).
// OUT16==1: store hout as bf16 (consumer is next k_gemm which converts to f16).
#define AGG_GATH(cv) (*(const ushort4*)(h16 + ((size_t)((cv) >> 32)) * 64 + lane * 4))
#define AGG_FMA(a, cv, h)                                     \
  {                                                           \
    float v_ = __uint_as_float((unsigned int)(cv));           \
    (a).x += v_ * BF2F((h).x); (a).y += v_ * BF2F((h).y);     \
    (a).z += v_ * BF2F((h).z); (a).w += v_ * BF2F((h).w);     \
  }
template <int STATS, int LRELU, int OUT16>
__launch_bounds__(256)
__global__ void k_agg(const unsigned short* __restrict__ h16, void* __restrict__ hout,
                      const float* __restrict__ bias, const float* __restrict__ dinv,
                      const int* __restrict__ rowstart,
                      const unsigned long long* __restrict__ colval,
                      float* __restrict__ partial, int N) {
  __shared__ float4 rs[STATS ? 256 : 1];
  __shared__ float4 rq[STATS ? 256 : 1];
  const int t = threadIdx.x;
  const int grp = t >> 4;
  const int lane = t & 15;
  const int d = blockIdx.x * 16 + grp;
  const bool valid = (d < N);
  int r0 = 0, r1 = 0;
  if (valid) { r0 = rowstart[d]; r1 = rowstart[d + 1]; }
  float4 a0 = make_float4(0.f, 0.f, 0.f, 0.f);
  float4 a1 = make_float4(0.f, 0.f, 0.f, 0.f);
  float4 a2 = make_float4(0.f, 0.f, 0.f, 0.f);
  float4 a3 = make_float4(0.f, 0.f, 0.f, 0.f);
  int r = r0;
  for (; r + 8 <= r1; r += 8) {
    unsigned long long cv0 = colval[r + 0];
    unsigned long long cv1 = colval[r + 1];
    unsigned long long cv2 = colval[r + 2];
    unsigned long long cv3 = colval[r + 3];
    unsigned long long cv4 = colval[r + 4];
    unsigned long long cv5 = colval[r + 5];
    unsigned long long cv6 = colval[r + 6];
    unsigned long long cv7 = colval[r + 7];
    ushort4 h0 = AGG_GATH(cv0);
    ushort4 h1 = AGG_GATH(cv1);
    ushort4 h2 = AGG_GATH(cv2);
    ushort4 h3 = AGG_GATH(cv3);
    ushort4 h4 = AGG_GATH(cv4);
    ushort4 h5 = AGG_GATH(cv5);
    ushort4 h6 = AGG_GATH(cv6);
    ushort4 h7 = AGG_GATH(cv7);
    AGG_FMA(a0, cv0, h0); AGG_FMA(a1, cv1, h1);
    AGG_FMA(a2, cv2, h2); AGG_FMA(a3, cv3, h3);
    AGG_FMA(a0, cv4, h4); AGG_FMA(a1, cv5, h5);
    AGG_FMA(a2, cv6, h6); AGG_FMA(a3, cv7, h7);
  }
  for (; r + 4 <= r1; r += 4) {
    unsigned long long cv0 = colval[r + 0];
    unsigned long long cv1 = colval[r + 1];
    unsigned long long cv2 = colval[r + 2];
    unsigned long long cv3 = colval[r + 3];
    ushort4 h0 = AGG_GATH(cv0);
    ushort4 h1 = AGG_GATH(cv1);
    ushort4 h2 = AGG_GATH(cv2);
    ushort4 h3 = AGG_GATH(cv3);
    AGG_FMA(a0, cv0, h0); AGG_FMA(a1, cv1, h1);
    AGG_FMA(a2, cv2, h2); AGG_FMA(a3, cv3, h3);
  }
  for (; r < r1; ++r) {
    unsigned long long cv = colval[r];
    ushort4 hv = AGG_GATH(cv);
    AGG_FMA(a0, cv, hv);
  }
  float4 acc;
  acc.x = (a0.x + a1.x) + (a2.x + a3.x);
  acc.y = (a0.y + a1.y) + (a2.y + a3.y);
  acc.z = (a0.z + a1.z) + (a2.z + a3.z);
  acc.w = (a0.w + a1.w) + (a2.w + a3.w);
  float di = valid ? dinv[d] : 0.f;
  ushort4 hd4 = make_ushort4(0, 0, 0, 0);
  if (valid) hd4 = *(const ushort4*)(h16 + (size_t)d * 64 + lane * 4);
  float4 b4 = *(const float4*)(bias + lane * 4);
  float4 o;
  o.x = di * (acc.x + BF2F(hd4.x)) + b4.x;
  o.y = di * (acc.y + BF2F(hd4.y)) + b4.y;
  o.z = di * (acc.z + BF2F(hd4.z)) + b4.z;
  o.w = di * (acc.w + BF2F(hd4.w)) + b4.w;
  if (LRELU) {
    o.x = (o.x > 0.f) ? o.x : LRELU_SLOPE * o.x;
    o.y = (o.y > 0.f) ? o.y : LRELU_SLOPE * o.y;
    o.z = (o.z > 0.f) ? o.z : LRELU_SLOPE * o.z;
    o.w = (o.w > 0.f) ? o.w : LRELU_SLOPE * o.w;
  }
  if (!valid) o = make_float4(0.f, 0.f, 0.f, 0.f);
  if (valid) {
    if (OUT16) {
      ushort4 o16;
      o16.x = f2bf(o.x); o16.y = f2bf(o.y); o16.z = f2bf(o.z); o16.w = f2bf(o.w);
      *(ushort4*)((unsigned short*)hout + (size_t)d * 64 + lane * 4) = o16;
    } else {
      *(float4*)((float*)hout + (size_t)d * 64 + lane * 4) = o;
    }
  }

  if (STATS) {
    rs[t] = o;
    rq[t] = make_float4(o.x * o.x, o.y * o.y, o.z * o.z, o.w * o.w);
    __syncthreads();
#pragma unroll
    for (int st = 8; st >= 1; st >>= 1) {
      if ((t >> 4) < st) {
        float4 sa = rs[t], sb = rs[t + st * 16];
        float4 qa = rq[t], qb = rq[t + st * 16];
        rs[t] = make_float4(sa.x + sb.x, sa.y + sb.y, sa.z + sb.z, sa.w + sb.w);
        rq[t] = make_float4(qa.x + qb.x, qa.y + qb.y, qa.z + qb.z, qa.w + qb.w);
      }
      __syncthreads();
    }
    if (t < 16) {
      float4 sv = rs[t], qv = rq[t];
      float* ps = partial + (size_t)blockIdx.x * 128 + 4 * t;
      ps[0] = sv.x; ps[1] = sv.y; ps[2] = sv.z; ps[3] = sv.w;
      ps[64] = qv.x; ps[65] = qv.y; ps[66] = qv.z; ps[67] = qv.w;
    }
  }
}

// Parallel reduce: 128 blocks (one per output column), 256 threads each.
__global__ void k_stats_reduce(const float* __restrict__ partial, float* __restrict__ s,
                               float* __restrict__ ss, int nb) {
  __shared__ float red[256];
  const int c = blockIdx.x;   // 0..127
  const int t = threadIdx.x;  // 0..255
  float a = 0.f;
  for (int b = t; b < nb; b += 256) a += partial[(size_t)b * 128 + c];
  red[t] = a;
  __syncthreads();
  for (int st = 128; st >= 1; st >>= 1) {
    if (t < st) red[t] += red[t + st];
    __syncthreads();
  }
  if (t == 0) {
    if (c < 64) s[c] = red[0];
    else ss[c - 64] = red[0];
  }
}

// ---------------- graph boundaries from sorted batch (atomic-free) ----------------
__global__ void k_gbounds(const int* __restrict__ batch, int* __restrict__ gstart,
                          int N, int G) {
  int i = blockIdx.x * blockDim.x + threadIdx.x;
  if (i >= N) return;
  int b = batch[i];
  int prev = (i == 0) ? -1 : batch[i - 1];
  for (int g = prev + 1; g <= b; ++g) gstart[g] = i;   // batch sorted => prev <= b
  if (i == N - 1) {
    for (int g = b + 1; g <= G; ++g) gstart[g] = N;
  }
}

// ---------------- pooling (max & mean per graph) + FC, fused ----------------
__launch_bounds__(256)
__global__ void k_pool(const float* __restrict__ h, const int* __restrict__ gstart,
                       const float* __restrict__ Wfc, const float* __restrict__ bfc,
                       float* __restrict__ out, int G) {
  __shared__ float lmx[256], lsm[256], red[128];
  const int g = blockIdx.x;
  const int t = threadIdx.x;
  const int c = t & 63;
  const int sub = t >> 6;
  const int n0 = gstart[g];
  const int n1 = gstart[g + 1];
  float mx = -INFINITY, sm = 0.f;
  for (int n = n0 + sub; n < n1; n += 4) {
    float v = h[(size_t)n * 64 + c];
    mx = fmaxf(mx, v);
    sm += v;
  }
  lmx[t] = mx;
  lsm[t] = sm;
  __syncthreads();
  if (t < 64) {
    mx = fmaxf(fmaxf(lmx[t], lmx[t + 64]), fmaxf(lmx[t + 128], lmx[t + 192]));
    sm = lsm[t] + lsm[t + 64] + lsm[t + 128] + lsm[t + 192];
    float cntf = (float)(n1 - n0);
    float mean = sm / fmaxf(cntf, 1.0f);
    red[t] = mx * Wfc[t];
    red[t + 64] = mean * Wfc[64 + t];
  }
  __syncthreads();
  for (int st = 64; st >= 1; st >>= 1) {
    if (t < st) red[t] += red[t + st];
    __syncthreads();
  }
  if (t == 0) out[g] = red[0] + bfc[0];
}

// ---------------- host launch ----------------
extern "C" void kernel_launch(void* const* d_in, const int* in_sizes, int n_in,
                              void* d_out, int out_size, void* d_ws, size_t ws_size,
                              hipStream_t stream) {
  const float* x = (const float*)d_in[0];
  const int* ei = (const int*)d_in[1];
  const int* batch = (const int*)d_in[2];
  const float* eattr = (const float*)d_in[3];
  const float* W0 = (const float*)d_in[4];
  const float* b0 = (const float*)d_in[5];
  const float* g0 = (const float*)d_in[6];
  const float* be0 = (const float*)d_in[7];
  const float* W1 = (const float*)d_in[8];
  const float* b1 = (const float*)d_in[9];
  const float* g1 = (const float*)d_in[10];
  const float* be1 = (const float*)d_in[11];
  const float* W2 = (const float*)d_in[12];
  const float* b2 = (const float*)d_in[13];
  const float* W3 = (const float*)d_in[14];
  const float* b3 = (const float*)d_in[15];
  const float* Wfc = (const float*)d_in[16];
  const float* bfc = (const float*)d_in[17];
  float* out = (float*)d_out;

  const int N = in_sizes[2];       // batch is [N]
  const int E = in_sizes[3];       // edge_attr is [E]
  const int CIN = in_sizes[0] / N; // 128
  const int G = out_size;          // [G,1]
  const int nbuck = ceil_div(N, 128);
  const int chunk = ceil_div(E, 256);
  const int M = nbuck * 256;       // hist matrix elements
  const int nag = ceil_div(N, 16); // k_agg blocks

  // workspace carve-up (256B-aligned slices)
  size_t off = 0;
  auto alloc = [&](size_t bytes) -> void* {
    void* p = (char*)d_ws + off;
    off += (bytes + 255) & ~(size_t)255;
    return p;
  };
  int* histT = (int*)alloc((size_t)1024 * 256 * 4);   // raw counts [bucket][block]
  int* histS = (int*)alloc((size_t)1024 * 256 * 4);   // scanned
  int* bsum = (int*)alloc(1024 * 4);
  unsigned long long* bucketed = (unsigned long long*)alloc((size_t)E * 8);
  float* dinv = (float*)alloc((size_t)N * 4);
  int* rowstart = (int*)alloc((size_t)(N + 1) * 4);
  unsigned long long* colval = (unsigned long long*)alloc((size_t)E * 8);
  unsigned short* A16 = (unsigned short*)alloc((size_t)N * 64 * 2);
  unsigned short* B16 = (unsigned short*)alloc((size_t)N * 64 * 2);
  float* A = (float*)alloc((size_t)N * 64 * 4);       // final layer out (pool input)
  unsigned short* H16 = (unsigned short*)alloc((size_t)N * 64 * 2);
  float* sums = (float*)alloc(256 * 4);   // s0|ss0|s1|ss1
  float* partial = (float*)alloc((size_t)nag * 128 * 4);
  int* gstart = (int*)alloc((size_t)(G + 1) * 4);
  (void)ws_size; (void)n_in; (void)CIN;

  // ---- graph structure (layer-invariant, zero device-scope atomics) ----
  b1_hist<<<256, 1024, 0, stream>>>(ei, histT, E, chunk, nbuck);
  const int nbs = ceil_div(M, 1024);
  scan1i<<<nbs, 256, 0, stream>>>(histT, histS, bsum, M);
  scan2i<<<1, 256, 0, stream>>>(bsum, nbs);
  scan3i<<<ceil_div(M, 256), 256, 0, stream>>>(histS, bsum, M);
  b3_scatter<<<256, 1024, 0, stream>>>(ei, eattr, histS, bucketed, E, chunk, nbuck);
  c_build<<<nbuck, 256, 0, stream>>>(bucketed, histS, rowstart, dinv, colval, N, E, nbuck);
  k_gbounds<<<ceil_div(N, 256), 256, 0, stream>>>(batch, gstart, N, G);

  // layer 0: gemm(x,W0)->H16 (dinv-scaled); agg(+stats) H16->B16; reduce
  k_gemm<128, 0, 0><<<ceil_div(N, 64), 256, 0, stream>>>(x, W0, H16, dinv, nullptr, nullptr, nullptr, nullptr, N);
  k_agg<1, 0, 1><<<nag, 256, 0, stream>>>(H16, B16, b0, dinv, rowstart, colval, partial, N);
  k_stats_reduce<<<128, 256, 0, stream>>>(partial, sums + 0, sums + 64, nag);

  // layer 1: gemm(bn0+lrelu(B16),W1)->H16 (fused); agg(+stats) H16->A16; reduce
  k_gemm<64, 1, 1><<<ceil_div(N, 64), 256, 0, stream>>>(B16, W1, H16, dinv, sums + 0, sums + 64, g0, be0, N);
  k_agg<1, 0, 1><<<nag, 256, 0, stream>>>(H16, A16, b1, dinv, rowstart, colval, partial, N);
  k_stats_reduce<<<128, 256, 0, stream>>>(partial, sums + 128, sums + 192, nag);

  // layer 2: gemm(bn1+lrelu(A16),W2)->H16 (fused); agg(+lrelu) H16->B16
  k_gemm<64, 1, 1><<<ceil_div(N, 64), 256, 0, stream>>>(A16, W2, H16, dinv, sums + 128, sums + 192, g1, be1, N);
  k_agg<0, 1, 1><<<nag, 256, 0, stream>>>(H16, B16, b2, dinv, rowstart, colval, nullptr, N);

  // layer 3: gemm(B16,W3)->H16; agg(+lrelu) H16->A (fp32 for pool)
  k_gemm<64, 0, 1><<<ceil_div(N, 64), 256, 0, stream>>>(B16, W3, H16, dinv, nullptr, nullptr, nullptr, nullptr, N);
  k_agg<0, 1, 0><<<nag, 256, 0, stream>>>(H16, A, b3, dinv, rowstart, colval, nullptr, N);

  // pooling + FC
  k_pool<<<G, 256, 0, stream>>>(A, gstart, Wfc, bfc, out, G);
}